// Round 9
// baseline (6115.117 us; speedup 1.0000x reference)
//
#include <hip/hip_runtime.h>
#include <stdint.h>

typedef uint32_t u32;
typedef __bf16 bf16;
typedef bf16 bf16x8 __attribute__((ext_vector_type(8)));
typedef float f32x4 __attribute__((ext_vector_type(4)));

#define B_ 256
#define T_ 256
#define H_ 1024
#define G_ 4096   // 4*H
#define NI_ 2048

// ---- workspace layout ----
static constexpr size_t OFF_W2T = 0;                            // 16 MB  [2][4096 vcg][1024 k] bf16
static constexpr size_t SZ_W2T  = (size_t)2 * G_ * H_ * 2;
static constexpr size_t OFF_LENS= OFF_W2T + SZ_W2T;             // 1 KB
static constexpr size_t OFF_RL  = OFF_LENS + 1024;              // 1 KB
static constexpr size_t OFF_BAR = OFF_RL + 1024;                // 144 KB
static constexpr size_t SZ_BAR  = 36864 * 4;
static constexpr size_t OFF_H   = OFF_BAR + SZ_BAR;             // [2 pp][2 dir][B][H] bf16 = 2 MB

static constexpr int LDS_BYTES = 131072;   // 64 vcols x 1024 k bf16, swizzled

__device__ __forceinline__ float bf2f(uint16_t b){ return __uint_as_float(((u32)b) << 16); }
__device__ __forceinline__ uint16_t f2bf(float f){
  u32 u = __float_as_uint(f);
  return (uint16_t)((u + 0x7fffu + ((u >> 16) & 1u)) >> 16);  // RNE
}
__device__ __forceinline__ float sigm(float x){ return 1.f / (1.f + __expf(-x)); }
__device__ __forceinline__ float tanh_(float x){ return 1.f - 2.f / (__expf(2.f * x) + 1.f); }

// threefry2x32, jax rotations
__device__ __forceinline__ void threefry(u32 k0, u32 k1, u32 x0, u32 x1, u32& o0, u32& o1){
  u32 ks2 = k0 ^ k1 ^ 0x1BD11BDAu;
  x0 += k0; x1 += k1;
#define TFR(r) { x0 += x1; x1 = (x1 << r) | (x1 >> (32 - r)); x1 ^= x0; }
  TFR(13) TFR(15) TFR(26) TFR(6)  x0 += k1;  x1 += ks2 + 1u;
  TFR(17) TFR(29) TFR(16) TFR(24) x0 += ks2; x1 += k0 + 2u;
  TFR(13) TFR(15) TFR(26) TFR(6)  x0 += k0;  x1 += k1 + 3u;
  TFR(17) TFR(29) TFR(16) TFR(24) x0 += k1;  x1 += ks2 + 4u;
  TFR(13) TFR(15) TFR(26) TFR(6)  x0 += ks2; x1 += k0 + 5u;
#undef TFR
  o0 = x0; o1 = x1;
}

__device__ __forceinline__ bool keep_mask(u32 idx){
  u32 o0, o1; threefry(0u, 42u, 0u, idx, o0, o1);
  return ((o0 ^ o1) & 0x80000000u) == 0u;
}

// ---- prep: Whh (1024, 4096) f32 -> w2t[d][vcg][k] bf16
__global__ __launch_bounds__(256) void k_prep_w(const float* __restrict__ whh_f,
                                                const float* __restrict__ whh_b,
                                                uint16_t* __restrict__ w2t){
  int bid = blockIdx.x;
  int d  = bid >> 12;
  int r  = bid & 4095;
  int kt = r >> 7;
  int ct = r & 127;
  const float* W = d ? whh_b : whh_f;
  __shared__ float tile[32][33];
  int tid = threadIdx.x;
  int lr = tid >> 5, lc = tid & 31;
#pragma unroll
  for (int i = 0; i < 4; i++)
    tile[lr + i*8][lc] = W[(size_t)(kt*32 + lr + i*8) * G_ + ct*32 + lc];
  __syncthreads();
  int colLocal = tid >> 3, kseg = tid & 7;
  int col = ct*32 + colLocal;
  int strip = col >> 10;
  int hcol  = col & 1023;
  int vcg = (hcol >> 4)*64 + strip*16 + (hcol & 15);
  size_t base = ((size_t)d * G_ + vcg) * H_ + kt*32 + kseg*4;
  u32 w0 = (u32)f2bf(tile[kseg*4+0][colLocal]) | ((u32)f2bf(tile[kseg*4+1][colLocal]) << 16);
  u32 w1 = (u32)f2bf(tile[kseg*4+2][colLocal]) | ((u32)f2bf(tile[kseg*4+3][colLocal]) << 16);
  uint2 v; v.x = w0; v.y = w1;
  *(uint2*)(w2t + base) = v;
}

// ---- init: zero h buffer 0 (first 1MB) + barrier counters; block 256 computes lens
__global__ __launch_bounds__(256) void k_init(uint16_t* __restrict__ hbuf,
                                              int* __restrict__ lens,
                                              u32* __restrict__ bar,
                                              const int* __restrict__ items){
  int bid = blockIdx.x, tid = threadIdx.x;
  if (bid == 256){
    int cnt = 0;
    for (int t = 0; t < T_; t++) cnt += (items[(size_t)tid * T_ + t] != 0) ? 1 : 0;
    lens[tid] = cnt;
    return;
  }
  size_t g = (size_t)bid * 256 + tid;                 // 65536 x 16B = 1MB
  ((uint4*)hbuf)[g] = make_uint4(0,0,0,0);
  if (tid < 36)
    ((uint4*)bar)[bid*36 + tid] = make_uint4(0,0,0,0);
}

// ---- asm helpers: NORMAL cached A loads; coherence via per-step buffer_inv (acquire fence)
#define A_LOAD(dst, base, IMM) \
  asm volatile("global_load_dwordx4 %0, %1, off offset:%2" \
    : "=v"(dst) : "v"(base), "i"(IMM) : "memory")
#define A_WAIT(N, r0, r1) \
  asm volatile("s_waitcnt vmcnt(%2)" : "+v"(r0), "+v"(r1) : "i"(N) : "memory")
#define AISS(j) { A_LOAD(pre0[(j)%12], p0, (j)*64); A_LOAD(pre1[(j)%12], p1, (j)*64); }

#define KS1(kk,st,bb) { \
  acc0[st] = __builtin_amdgcn_mfma_f32_16x16x32_bf16(a0_, bb, acc0[st], 0,0,0); \
  acc1[st] = __builtin_amdgcn_mfma_f32_16x16x32_bf16(a1_, bb, acc1[st], 0,0,0); }

#define KSTEP(kk) { \
  bf16x8 bb0 = *(const bf16x8*)(smem + qoff00 +          (((kk)&1)?qd1:qd0) + (((kk)&30)<<6)); \
  bf16x8 bb1 = *(const bf16x8*)(smem + qoff00 + 32768  + (((kk)&1)?qd1:qd0) + (((kk)&30)<<6)); \
  bf16x8 bb2 = *(const bf16x8*)(smem + qoff00 + 65536  + (((kk)&1)?qd1:qd0) + (((kk)&30)<<6)); \
  bf16x8 bb3 = *(const bf16x8*)(smem + qoff00 + 98304  + (((kk)&1)?qd1:qd0) + (((kk)&30)<<6)); \
  A_WAIT(((kk)<=20 ? 22 : 62-2*(kk)), pre0[(kk)%12], pre1[(kk)%12]); \
  bf16x8 a0_ = pre0[(kk)%12]; bf16x8 a1_ = pre1[(kk)%12]; \
  KS1(kk,0,bb0) KS1(kk,1,bb1) KS1(kk,2,bb2) KS1(kk,3,bb3) \
  if ((kk) < 20) { AISS((kk)+12); } }

#define R4(M,a) M(a) M((a)+1) M((a)+2) M((a)+3)
#define R12(M,a) R4(M,a) R4(M,(a)+4) R4(M,(a)+8)
#define R16(M,a) R4(M,a) R4(M,(a)+4) R4(M,(a)+8) R4(M,(a)+12)

// ---- persistent bidirectional LSTM. 256 blocks x 256 threads, cooperative launch.
// h stores: sc0sc1 write-through (L2 never dirty, MALL owns fresh h).
// h loads: normal cached; per-step agent-acquire fence (buffer_inv) after the barrier.
__global__ __launch_bounds__(256, 1) void k_persist(
    const int* __restrict__ items, const int* __restrict__ actions,
    const float* __restrict__ wt_f, const float* __restrict__ wt_b,
    const float* __restrict__ bias_f, const float* __restrict__ bias_b,
    const uint16_t* __restrict__ w2t, uint16_t* __restrict__ hbuf,
    const int* __restrict__ lens, u32* __restrict__ bar)
{
  extern __shared__ char smem[];
  const int bid = blockIdx.x;
  const int d = bid >> 7;
  const int m = (bid >> 6) & 1;
  const int n = bid & 63;
  const int tid = threadIdx.x;
  const int b0 = m * 128;
  const int ncol = n * 16;
  const float* wt   = d ? wt_b : wt_f;
  const float* bias = d ? bias_b : bias_f;

  // --- W slice -> LDS, XOR-swizzled along k ---
  {
    const char* wsrc = (const char*)(w2t + ((size_t)d * G_ + n*64) * H_);
#pragma unroll
    for (int i = 0; i < 32; i++){
      int u = i*256 + tid;
      int row = u >> 7, seg = u & 127;
      int sb = seg * 16;
      uint4 v = *(const uint4*)(wsrc + row*2048 + sb);
      *(uint4*)(smem + row*2048 + (sb ^ ((row & 7) << 4))) = v;
    }
  }

  const int w  = tid >> 6;
  const int l  = tid & 63;
  const int c  = l & 15;
  const int lk = l >> 4;
  const int gc = ncol + c;

  // --- per-lane constants: action rows + bias ---
  float xav0[4], xav1[4], xav2[4];
#pragma unroll
  for (int st = 0; st < 4; st++){
    xav0[st] = wt[(size_t)(NI_ + 0) * G_ + st*1024 + gc] + bias[st*1024 + gc];
    xav1[st] = wt[(size_t)(NI_ + 1) * G_ + st*1024 + gc] + bias[st*1024 + gc];
    xav2[st] = wt[(size_t)(NI_ + 2) * G_ + st*1024 + gc] + bias[st*1024 + gc];
  }

  int len_r[8];
#pragma unroll
  for (int i = 0; i < 8; i++)
    len_r[i] = lens[b0 + w*32 + (i>>2)*16 + lk*4 + (i&3)];

  // --- gather pipeline state ---
  int itB[8], acB[8], acA[8];
  float xg[8][4];
  {
    const int ta = d ? (T_-1) : 0;
#pragma unroll
    for (int i = 0; i < 8; i++){
      int row = b0 + w*32 + (i>>2)*16 + lk*4 + (i&3);
      itB[i] = items[(size_t)row * T_ + ta];
      acB[i] = actions[(size_t)row * T_ + ta];
    }
#pragma unroll
    for (int i = 0; i < 8; i++){
      const float* wr = wt + (size_t)itB[i] * G_ + gc;
#pragma unroll
      for (int st = 0; st < 4; st++) xg[i][st] = wr[st*1024];
      acA[i] = acB[i];
    }
    const int tb = d ? (T_-2) : 1;
#pragma unroll
    for (int i = 0; i < 8; i++){
      int row = b0 + w*32 + (i>>2)*16 + lk*4 + (i&3);
      itB[i] = items[(size_t)row * T_ + tb];
      acB[i] = actions[(size_t)row * T_ + tb];
    }
  }

  // LDS b-read offset pieces
  const int key  = (c & 7) << 4;
  const int kbit = (c >> 2) & 1;
  const u32 qoff00 = (u32)(c*2048 + ((lk*16) ^ (key & 48)));
  const u32 qd0 = (u32)((kbit) << 6);
  const u32 qd1 = (u32)((1 ^ kbit) << 6);

  float c_reg[8]; uint16_t h_reg[8];
#pragma unroll
  for (int i = 0; i < 8; i++){ c_reg[i] = 0.f; h_reg[i] = 0; }

  __syncthreads();   // W LDS ready

  bf16x8 pre0[12], pre1[12];

  for (int s = 0; s < T_; s++){
    const int t = d ? (T_-1-s) : s;

    // --- acc init (pure VALU: xg prefetched + action-row select) ---
    f32x4 acc0[4], acc1[4];
#pragma unroll
    for (int r4 = 0; r4 < 4; r4++){
#pragma unroll
      for (int st = 0; st < 4; st++){
        float xa0 = (acA[r4]   == 0) ? xav0[st] : ((acA[r4]   == 1) ? xav1[st] : xav2[st]);
        float xa1 = (acA[4+r4] == 0) ? xav0[st] : ((acA[4+r4] == 1) ? xav1[st] : xav2[st]);
        acc0[st][r4] = xg[r4][st]   + xa0;
        acc1[st][r4] = xg[4+r4][st] + xa1;
      }
    }
    asm volatile("s_waitcnt vmcnt(0)" ::: "memory");   // clean vmcnt before counted pipeline
    __builtin_amdgcn_sched_barrier(0);

    const uint16_t* hin  = hbuf + (size_t)((s&1)*2 + d)     * (size_t)(B_*H_);
    uint16_t*       hout = hbuf + (size_t)(((s&1)^1)*2 + d) * (size_t)(B_*H_);
    const char* p0 = (const char*)hin + (size_t)(b0 + w*32 + c)*2048 + lk*16;
    const char* p1 = p0 + 16*2048;

    // --- prologue: 12 pairs of A loads in flight ---
    R12(AISS, 0)
    // --- k-loop: 32 fully-unrolled iterations ---
    R16(KSTEP, 0)
    R16(KSTEP, 16)
    __builtin_amdgcn_sched_barrier(0);

    // --- epilogue: gates in registers, coherent h stores ---
#pragma unroll
    for (int mi = 0; mi < 2; mi++)
#pragma unroll
      for (int r4 = 0; r4 < 4; r4++){
        int i8 = mi*4 + r4;
        int row = b0 + w*32 + mi*16 + lk*4 + r4;
        float g0 = mi ? acc1[0][r4] : acc0[0][r4];
        float g1 = mi ? acc1[1][r4] : acc0[1][r4];
        float g2 = mi ? acc1[2][r4] : acc0[2][r4];
        float g3 = mi ? acc1[3][r4] : acc0[3][r4];
        if (t < len_r[i8]){
          float i_ = sigm(g0);
          float f_ = sigm(g1);
          float gg = tanh_(g2);
          float o_ = sigm(g3);
          float cn = f_ * c_reg[i8] + i_ * gg;
          c_reg[i8] = cn;
          h_reg[i8] = f2bf(o_ * tanh_(cn));
        }
        const uint16_t* addr = hout + (size_t)row * H_ + gc;
        u32 hv = h_reg[i8];
        asm volatile("global_store_short %0, %1, off sc0 sc1" :: "v"(addr), "v"(hv) : "memory");
      }
    asm volatile("s_waitcnt vmcnt(0)" ::: "memory");
    __syncthreads();
    if (s == T_-1) break;

    // --- global barrier arrive (release: nothing dirty in L2 -> cheap) ---
    u32* arr = bar + ((u32)s*8 + (u32)(bid & 7))*16;
    u32* fin = bar + 32768 + (u32)s*16;
    if (tid == 0){
      u32 old = __hip_atomic_fetch_add(arr, 1u, __ATOMIC_RELEASE, __HIP_MEMORY_SCOPE_AGENT);
      if (old == 31u)
        __hip_atomic_fetch_add(fin, 1u, __ATOMIC_RELEASE, __HIP_MEMORY_SCOPE_AGENT);
    }
    // --- overlap with barrier: issue gather for step s+1, index loads for s+2 ---
#pragma unroll
    for (int i = 0; i < 8; i++){
      const float* wr = wt + (size_t)itB[i] * G_ + gc;
#pragma unroll
      for (int st = 0; st < 4; st++) xg[i][st] = wr[st*1024];
      acA[i] = acB[i];
    }
    {
      int t2 = d ? (T_-1-(s+2)) : (s+2);
      if (t2 < 0) t2 = 0;
      if (t2 > T_-1) t2 = T_-1;
#pragma unroll
      for (int i = 0; i < 8; i++){
        int row = b0 + w*32 + (i>>2)*16 + lk*4 + (i&3);
        itB[i] = items[(size_t)row * T_ + t2];
        acB[i] = actions[(size_t)row * T_ + t2];
      }
    }
    if (tid == 0){
      while (__hip_atomic_load(fin, __ATOMIC_RELAXED, __HIP_MEMORY_SCOPE_AGENT) < 8u)
        __builtin_amdgcn_s_sleep(2);
    }
    __syncthreads();
    // acquire: invalidate L1/L2 so this step's h reads see MALL-fresh data
    __builtin_amdgcn_fence(__ATOMIC_ACQUIRE, "agent");
  }
}

// ---- FC + per-row loss ----
__global__ __launch_bounds__(256) void k_fc(const uint16_t* __restrict__ hfin,
    const float* __restrict__ wfc, const float* __restrict__ bfc,
    const int* __restrict__ targets, float* __restrict__ rowloss){
  int b = blockIdx.x, tid = threadIdx.x;
  float a0 = 0.f, a1 = 0.f;
  for (int jj = tid; jj < 2*H_; jj += 256){
    int d = jj >> 10, j = jj & 1023;
    float h = bf2f(hfin[(size_t)d * B_ * H_ + (size_t)b * H_ + j]);
    u32 idx = (u32)(d * (B_ * H_) + b * H_ + j);
    float feat = keep_mask(idx) ? (2.f * h) : 0.f;
    a0 += feat * wfc[jj*2 + 0];
    a1 += feat * wfc[jj*2 + 1];
  }
#pragma unroll
  for (int off = 32; off > 0; off >>= 1){
    a0 += __shfl_down(a0, off, 64);
    a1 += __shfl_down(a1, off, 64);
  }
  __shared__ float r0[4], r1[4];
  if ((tid & 63) == 0){ r0[tid >> 6] = a0; r1[tid >> 6] = a1; }
  __syncthreads();
  if (tid == 0){
    float l0 = r0[0]+r0[1]+r0[2]+r0[3] + bfc[0];
    float l1 = r1[0]+r1[1]+r1[2]+r1[3] + bfc[1];
    float mx = fmaxf(l0, l1);
    float lse = mx + logf(__expf(l0 - mx) + __expf(l1 - mx));
    rowloss[b] = lse - (targets[b] ? l1 : l0);
  }
}

__global__ __launch_bounds__(256) void k_loss(const float* __restrict__ rowloss, float* __restrict__ out){
  int tid = threadIdx.x;
  float v = rowloss[tid];
#pragma unroll
  for (int off = 32; off > 0; off >>= 1) v += __shfl_down(v, off, 64);
  __shared__ float r[4];
  if ((tid & 63) == 0) r[tid >> 6] = v;
  __syncthreads();
  if (tid == 0) out[0] = (r[0] + r[1] + r[2] + r[3]) * (1.f / B_);
}

extern "C" void kernel_launch(void* const* d_in, const int* in_sizes, int n_in,
                              void* d_out, int out_size, void* d_ws, size_t ws_size,
                              hipStream_t stream){
  (void)in_sizes; (void)n_in; (void)out_size; (void)ws_size;
  const int*   items   = (const int*)  d_in[0];
  const int*   actions = (const int*)  d_in[1];
  const int*   targets = (const int*)  d_in[2];
  const float* wt_f    = (const float*)d_in[3];
  const float* whh_f   = (const float*)d_in[4];
  const float* b_f     = (const float*)d_in[5];
  const float* wt_b    = (const float*)d_in[6];
  const float* whh_b   = (const float*)d_in[7];
  const float* b_b     = (const float*)d_in[8];
  const float* wfc     = (const float*)d_in[9];
  const float* bfc     = (const float*)d_in[10];

  char* ws = (char*)d_ws;
  uint16_t* w2t   = (uint16_t*)(ws + OFF_W2T);
  int*      lens  = (int*)     (ws + OFF_LENS);
  float*    rlbuf = (float*)   (ws + OFF_RL);
  u32*      bar   = (u32*)     (ws + OFF_BAR);
  uint16_t* hbuf  = (uint16_t*)(ws + OFF_H);

  hipFuncSetAttribute((const void*)k_persist,
                      hipFuncAttributeMaxDynamicSharedMemorySize, LDS_BYTES);

  hipLaunchKernelGGL(k_prep_w, dim3(8192), dim3(256), 0, stream, whh_f, whh_b, w2t);
  hipLaunchKernelGGL(k_init,   dim3(257),  dim3(256), 0, stream, hbuf, lens, bar, items);

  void* args[] = { (void*)&items, (void*)&actions, (void*)&wt_f, (void*)&wt_b,
                   (void*)&b_f, (void*)&b_b, (void*)&w2t, (void*)&hbuf,
                   (void*)&lens, (void*)&bar };
  hipLaunchCooperativeKernel((const void*)k_persist, dim3(256), dim3(256),
                             args, LDS_BYTES, stream);

  hipLaunchKernelGGL(k_fc,   dim3(256), dim3(256), 0, stream, hbuf, wfc, bfc, targets, rlbuf);
  hipLaunchKernelGGL(k_loss, dim3(1),   dim3(256), 0, stream, rlbuf, (float*)d_out);
}

// Round 10
// 3597.692 us; speedup vs baseline: 1.6997x; 1.6997x over previous
//
#include <hip/hip_runtime.h>
#include <stdint.h>

typedef uint32_t u32;
typedef __bf16 bf16;
typedef bf16 bf16x8 __attribute__((ext_vector_type(8)));
typedef float f32x4 __attribute__((ext_vector_type(4)));

#define B_ 256
#define T_ 256
#define H_ 1024
#define G_ 4096   // 4*H
#define NI_ 2048

// ---- workspace layout ----
static constexpr size_t OFF_W2T = 0;                            // 16 MB  [2][4096 vcg][1024 k] bf16
static constexpr size_t SZ_W2T  = (size_t)2 * G_ * H_ * 2;
static constexpr size_t OFF_LENS= OFF_W2T + SZ_W2T;             // 1 KB
static constexpr size_t OFF_RL  = OFF_LENS + 1024;              // 1 KB
static constexpr size_t OFF_BAR = OFF_RL + 1024;                // 4 KB (accumulating counters)
static constexpr size_t SZ_BAR  = 4096;
static constexpr size_t OFF_H   = OFF_BAR + SZ_BAR;             // R x [2 dir][64 n][256 row][16 col] bf16
static constexpr size_t SZ_HBUF = (size_t)2 * B_ * H_ * 2;      // 1 MB per rotation slot

static constexpr int LDS_BYTES = 131072;   // 64 vcols x 1024 k bf16, swizzled

__device__ __forceinline__ float bf2f(uint16_t b){ return __uint_as_float(((u32)b) << 16); }
__device__ __forceinline__ uint16_t f2bf(float f){
  u32 u = __float_as_uint(f);
  return (uint16_t)((u + 0x7fffu + ((u >> 16) & 1u)) >> 16);  // RNE
}
__device__ __forceinline__ float sigm(float x){ return 1.f / (1.f + __expf(-x)); }
__device__ __forceinline__ float tanh_(float x){ return 1.f - 2.f / (__expf(2.f * x) + 1.f); }

// threefry2x32, jax rotations
__device__ __forceinline__ void threefry(u32 k0, u32 k1, u32 x0, u32 x1, u32& o0, u32& o1){
  u32 ks2 = k0 ^ k1 ^ 0x1BD11BDAu;
  x0 += k0; x1 += k1;
#define TFR(r) { x0 += x1; x1 = (x1 << r) | (x1 >> (32 - r)); x1 ^= x0; }
  TFR(13) TFR(15) TFR(26) TFR(6)  x0 += k1;  x1 += ks2 + 1u;
  TFR(17) TFR(29) TFR(16) TFR(24) x0 += ks2; x1 += k0 + 2u;
  TFR(13) TFR(15) TFR(26) TFR(6)  x0 += k0;  x1 += k1 + 3u;
  TFR(17) TFR(29) TFR(16) TFR(24) x0 += k1;  x1 += ks2 + 4u;
  TFR(13) TFR(15) TFR(26) TFR(6)  x0 += ks2; x1 += k0 + 5u;
#undef TFR
  o0 = x0; o1 = x1;
}

__device__ __forceinline__ bool keep_mask(u32 idx){
  u32 o0, o1; threefry(0u, 42u, 0u, idx, o0, o1);
  return ((o0 ^ o1) & 0x80000000u) == 0u;
}

// ---- prep: Whh (1024, 4096) f32 -> w2t[d][vcg][k] bf16
__global__ __launch_bounds__(256) void k_prep_w(const float* __restrict__ whh_f,
                                                const float* __restrict__ whh_b,
                                                uint16_t* __restrict__ w2t){
  int bid = blockIdx.x;
  int d  = bid >> 12;
  int r  = bid & 4095;
  int kt = r >> 7;
  int ct = r & 127;
  const float* W = d ? whh_b : whh_f;
  __shared__ float tile[32][33];
  int tid = threadIdx.x;
  int lr = tid >> 5, lc = tid & 31;
#pragma unroll
  for (int i = 0; i < 4; i++)
    tile[lr + i*8][lc] = W[(size_t)(kt*32 + lr + i*8) * G_ + ct*32 + lc];
  __syncthreads();
  int colLocal = tid >> 3, kseg = tid & 7;
  int col = ct*32 + colLocal;
  int strip = col >> 10;
  int hcol  = col & 1023;
  int vcg = (hcol >> 4)*64 + strip*16 + (hcol & 15);
  size_t base = ((size_t)d * G_ + vcg) * H_ + kt*32 + kseg*4;
  u32 w0 = (u32)f2bf(tile[kseg*4+0][colLocal]) | ((u32)f2bf(tile[kseg*4+1][colLocal]) << 16);
  u32 w1 = (u32)f2bf(tile[kseg*4+2][colLocal]) | ((u32)f2bf(tile[kseg*4+3][colLocal]) << 16);
  uint2 v; v.x = w0; v.y = w1;
  *(uint2*)(w2t + base) = v;
}

// ---- init: zero h rotation slot 0 (1 MB) + barrier counters; block 256 computes lens
__global__ __launch_bounds__(256) void k_init(uint16_t* __restrict__ hbuf,
                                              int* __restrict__ lens,
                                              u32* __restrict__ bar,
                                              const int* __restrict__ items){
  int bid = blockIdx.x, tid = threadIdx.x;
  if (bid == 256){
    int cnt = 0;
    for (int t = 0; t < T_; t++) cnt += (items[(size_t)tid * T_ + t] != 0) ? 1 : 0;
    lens[tid] = cnt;
    return;
  }
  size_t g = (size_t)bid * 256 + tid;                 // 65536 x 16B = 1MB
  ((uint4*)hbuf)[g] = make_uint4(0,0,0,0);
  if (bid == 0 && tid < 256)
    ((uint4*)bar)[tid] = make_uint4(0,0,0,0);         // 4 KB
}

// ---- asm helpers ----
#define A_LOADC(dst, base, IMM) \
  asm volatile("global_load_dwordx4 %0, %1, off offset:%2 sc0 sc1" \
    : "=v"(dst) : "v"(base), "i"(IMM) : "memory")
#define A_LOADN(dst, base, IMM) \
  asm volatile("global_load_dwordx4 %0, %1, off offset:%2" \
    : "=v"(dst) : "v"(base), "i"(IMM) : "memory")
#define A_WAIT(N, r0, r1) \
  asm volatile("s_waitcnt vmcnt(%2)" : "+v"(r0), "+v"(r1) : "i"(N) : "memory")
#define AISS(j) { if constexpr (CACHED) { \
    A_LOADN(pre0[(j)%12], pA + (size_t)(j)*16384, 0); \
    A_LOADN(pre1[(j)%12], pA + (size_t)(j)*16384, 512); \
  } else { \
    A_LOADC(pre0[(j)%12], pA + (size_t)(j)*16384, 0); \
    A_LOADC(pre1[(j)%12], pA + (size_t)(j)*16384, 512); } }

#define KS1(kk,st,bb) { \
  acc0[st] = __builtin_amdgcn_mfma_f32_16x16x32_bf16(a0_, bb, acc0[st], 0,0,0); \
  acc1[st] = __builtin_amdgcn_mfma_f32_16x16x32_bf16(a1_, bb, acc1[st], 0,0,0); }

#define KSTEP(kk) { \
  bf16x8 bb0 = *(const bf16x8*)(smem + qoff00 +          (((kk)&1)?qd1:qd0) + (((kk)&30)<<6)); \
  bf16x8 bb1 = *(const bf16x8*)(smem + qoff00 + 32768  + (((kk)&1)?qd1:qd0) + (((kk)&30)<<6)); \
  bf16x8 bb2 = *(const bf16x8*)(smem + qoff00 + 65536  + (((kk)&1)?qd1:qd0) + (((kk)&30)<<6)); \
  bf16x8 bb3 = *(const bf16x8*)(smem + qoff00 + 98304  + (((kk)&1)?qd1:qd0) + (((kk)&30)<<6)); \
  A_WAIT(((kk)<=20 ? 22 : 62-2*(kk)), pre0[(kk)%12], pre1[(kk)%12]); \
  bf16x8 a0_ = pre0[(kk)%12]; bf16x8 a1_ = pre1[(kk)%12]; \
  KS1(kk,0,bb0) KS1(kk,1,bb1) KS1(kk,2,bb2) KS1(kk,3,bb3) \
  if ((kk) < 20) { AISS((kk)+12); } }

#define R4(M,a) M(a) M((a)+1) M((a)+2) M((a)+3)
#define R12(M,a) R4(M,a) R4(M,(a)+4) R4(M,(a)+8)
#define R16(M,a) R4(M,a) R4(M,(a)+4) R4(M,(a)+8) R4(M,(a)+12)

// ---- persistent bidirectional LSTM. 256 blocks x 256 threads, cooperative launch.
// h layout: [slot][dir][n=64][row=256][col=16] bf16 -> every 128B line has ONE writer block.
// Group (d,m) = 64 blocks on 2 XCDs (bid%8 heuristic); panels never cross groups.
// CACHED: normal A-loads + fence(acquire,agent) every (rmask+1) steps over rotation slots.
// !CACHED: sc0sc1 A-loads, ping-pong slots, no fence (round-7/8 behavior).
template <bool CACHED>
__global__ __launch_bounds__(256, 1) void k_persist(
    const int* __restrict__ items, const int* __restrict__ actions,
    const float* __restrict__ wt_f, const float* __restrict__ wt_b,
    const float* __restrict__ bias_f, const float* __restrict__ bias_b,
    const uint16_t* __restrict__ w2t, uint16_t* __restrict__ hbuf,
    const int* __restrict__ lens, u32* __restrict__ bar, int rmask)
{
  extern __shared__ char smem[];
  const int bid = blockIdx.x;
  // XCD-grouped swizzle: group g=(d,m) -> XCDs {2g, 2g+1}
  const int g = (bid >> 1) & 3;
  const int n = ((bid >> 3) << 1) | (bid & 1);
  const int d = g >> 1;
  const int m = g & 1;
  const int tid = threadIdx.x;
  const int b0 = m * 128;
  const int ncol = n * 16;
  const float* wt   = d ? wt_b : wt_f;
  const float* bias = d ? bias_b : bias_f;

  // --- W slice -> LDS, XOR-swizzled along k ---
  {
    const char* wsrc = (const char*)(w2t + ((size_t)d * G_ + n*64) * H_);
#pragma unroll
    for (int i = 0; i < 32; i++){
      int u = i*256 + tid;
      int row = u >> 7, seg = u & 127;
      int sb = seg * 16;
      uint4 v = *(const uint4*)(wsrc + row*2048 + sb);
      *(uint4*)(smem + row*2048 + (sb ^ ((row & 7) << 4))) = v;
    }
  }

  const int w  = tid >> 6;
  const int l  = tid & 63;
  const int c  = l & 15;
  const int lk = l >> 4;
  const int gc = ncol + c;

  // --- per-lane constants: action rows + bias ---
  float xav0[4], xav1[4], xav2[4];
#pragma unroll
  for (int st = 0; st < 4; st++){
    xav0[st] = wt[(size_t)(NI_ + 0) * G_ + st*1024 + gc] + bias[st*1024 + gc];
    xav1[st] = wt[(size_t)(NI_ + 1) * G_ + st*1024 + gc] + bias[st*1024 + gc];
    xav2[st] = wt[(size_t)(NI_ + 2) * G_ + st*1024 + gc] + bias[st*1024 + gc];
  }

  int len_r[8];
#pragma unroll
  for (int i = 0; i < 8; i++)
    len_r[i] = lens[b0 + w*32 + (i>>2)*16 + lk*4 + (i&3)];

  // --- gather pipeline state ---
  int itB[8], acB[8], acA[8];
  float xg[8][4];
  {
    const int ta = d ? (T_-1) : 0;
#pragma unroll
    for (int i = 0; i < 8; i++){
      int row = b0 + w*32 + (i>>2)*16 + lk*4 + (i&3);
      itB[i] = items[(size_t)row * T_ + ta];
      acB[i] = actions[(size_t)row * T_ + ta];
    }
#pragma unroll
    for (int i = 0; i < 8; i++){
      const float* wr = wt + (size_t)itB[i] * G_ + gc;
#pragma unroll
      for (int st = 0; st < 4; st++) xg[i][st] = wr[st*1024];
      acA[i] = acB[i];
    }
    const int tb = d ? (T_-2) : 1;
#pragma unroll
    for (int i = 0; i < 8; i++){
      int row = b0 + w*32 + (i>>2)*16 + lk*4 + (i&3);
      itB[i] = items[(size_t)row * T_ + tb];
      acB[i] = actions[(size_t)row * T_ + tb];
    }
  }

  // LDS b-read offset pieces
  const int key  = (c & 7) << 4;
  const int kbit = (c >> 2) & 1;
  const u32 qoff00 = (u32)(c*2048 + ((lk*16) ^ (key & 48)));
  const u32 qd0 = (u32)((kbit) << 6);
  const u32 qd1 = (u32)((1 ^ kbit) << 6);

  float c_reg[8]; uint16_t h_reg[8];
#pragma unroll
  for (int i = 0; i < 8; i++){ c_reg[i] = 0.f; h_reg[i] = 0; }

  __syncthreads();   // W LDS ready

  bf16x8 pre0[12], pre1[12];

  for (int s = 0; s < T_; s++){
    const int t = d ? (T_-1-s) : s;

    // periodic L2 invalidate: kills stale clean copies before a slot is re-read
    if (CACHED && s != 0 && (s & rmask) == 0)
      __builtin_amdgcn_fence(__ATOMIC_ACQUIRE, "agent");

    // --- acc init (pure VALU: xg prefetched + action-row select) ---
    f32x4 acc0[4], acc1[4];
#pragma unroll
    for (int r4 = 0; r4 < 4; r4++){
#pragma unroll
      for (int st = 0; st < 4; st++){
        float xa0 = (acA[r4]   == 0) ? xav0[st] : ((acA[r4]   == 1) ? xav1[st] : xav2[st]);
        float xa1 = (acA[4+r4] == 0) ? xav0[st] : ((acA[4+r4] == 1) ? xav1[st] : xav2[st]);
        acc0[st][r4] = xg[r4][st]   + xa0;
        acc1[st][r4] = xg[4+r4][st] + xa1;
      }
    }
    asm volatile("s_waitcnt vmcnt(0)" ::: "memory");   // clean vmcnt before counted pipeline
    __builtin_amdgcn_sched_barrier(0);

    const size_t bin  = (size_t)((s & rmask)*2 + d)     * (size_t)(B_*H_);
    const size_t bout = (size_t)((((s+1) & rmask))*2 + d) * (size_t)(B_*H_);
    const uint16_t* hin  = hbuf + bin;
    uint16_t*       hout = hbuf + bout;
    // A-fragment base: panel p = kk*2 + (lk>>1); addr = p*8192 + row*32 + (lk&1)*16
    const char* pA = (const char*)hin + (size_t)(b0 + w*32 + c)*32
                   + (size_t)(lk >> 1)*8192 + (size_t)(lk & 1)*16;

    // --- prologue: 12 pairs of A loads in flight ---
    R12(AISS, 0)
    // --- k-loop: 32 fully-unrolled iterations ---
    R16(KSTEP, 0)
    R16(KSTEP, 16)
    __builtin_amdgcn_sched_barrier(0);

    // --- epilogue: gates in registers, write-through h stores ---
#pragma unroll
    for (int mi = 0; mi < 2; mi++)
#pragma unroll
      for (int r4 = 0; r4 < 4; r4++){
        int i8 = mi*4 + r4;
        int row = b0 + w*32 + mi*16 + lk*4 + r4;
        float g0 = mi ? acc1[0][r4] : acc0[0][r4];
        float g1 = mi ? acc1[1][r4] : acc0[1][r4];
        float g2 = mi ? acc1[2][r4] : acc0[2][r4];
        float g3 = mi ? acc1[3][r4] : acc0[3][r4];
        if (t < len_r[i8]){
          float i_ = sigm(g0);
          float f_ = sigm(g1);
          float gg = tanh_(g2);
          float o_ = sigm(g3);
          float cn = f_ * c_reg[i8] + i_ * gg;
          c_reg[i8] = cn;
          h_reg[i8] = f2bf(o_ * tanh_(cn));
        }
        const uint16_t* addr = hout + (size_t)n*4096 + (size_t)row*16 + c;
        u32 hv = h_reg[i8];
        asm volatile("global_store_short %0, %1, off sc0 sc1" :: "v"(addr), "v"(hv) : "memory");
      }
    asm volatile("s_waitcnt vmcnt(0)" ::: "memory");
    __syncthreads();
    if (s == T_-1) break;

    // --- per-group barrier arrive (accumulating counters, release) ---
    u32* arr = bar + ((u32)g*8 + (u32)(n & 7))*16;
    u32* fin = bar + 512 + (u32)g*16;
    if (tid == 0){
      u32 old = __hip_atomic_fetch_add(arr, 1u, __ATOMIC_RELEASE, __HIP_MEMORY_SCOPE_AGENT);
      if ((old & 7u) == 7u)
        __hip_atomic_fetch_add(fin, 1u, __ATOMIC_RELEASE, __HIP_MEMORY_SCOPE_AGENT);
    }
    // --- overlap with barrier: issue gather for step s+1, index loads for s+2 ---
#pragma unroll
    for (int i = 0; i < 8; i++){
      const float* wr = wt + (size_t)itB[i] * G_ + gc;
#pragma unroll
      for (int st = 0; st < 4; st++) xg[i][st] = wr[st*1024];
      acA[i] = acB[i];
    }
    {
      int t2 = d ? (T_-1-(s+2)) : (s+2);
      if (t2 < 0) t2 = 0;
      if (t2 > T_-1) t2 = T_-1;
#pragma unroll
      for (int i = 0; i < 8; i++){
        int row = b0 + w*32 + (i>>2)*16 + lk*4 + (i&3);
        itB[i] = items[(size_t)row * T_ + t2];
        acB[i] = actions[(size_t)row * T_ + t2];
      }
    }
    if (tid == 0){
      const u32 target = 8u * (u32)(s + 1);
      while (__hip_atomic_load(fin, __ATOMIC_RELAXED, __HIP_MEMORY_SCOPE_AGENT) < target)
        __builtin_amdgcn_s_sleep(2);
    }
    __syncthreads();
  }
}

// ---- FC + per-row loss (h layout [d][n][256][16]) ----
__global__ __launch_bounds__(256) void k_fc(const uint16_t* __restrict__ hfin,
    const float* __restrict__ wfc, const float* __restrict__ bfc,
    const int* __restrict__ targets, float* __restrict__ rowloss){
  int b = blockIdx.x, tid = threadIdx.x;
  float a0 = 0.f, a1 = 0.f;
  for (int jj = tid; jj < 2*H_; jj += 256){
    int d = jj >> 10, j = jj & 1023;
    size_t addr = (size_t)d * B_ * H_ + (size_t)(j >> 4) * 4096 + (size_t)b * 16 + (j & 15);
    float h = bf2f(hfin[addr]);
    u32 idx = (u32)(d * (B_ * H_) + b * H_ + j);     // logical (2,B,H) index for dropout
    float feat = keep_mask(idx) ? (2.f * h) : 0.f;
    a0 += feat * wfc[jj*2 + 0];
    a1 += feat * wfc[jj*2 + 1];
  }
#pragma unroll
  for (int off = 32; off > 0; off >>= 1){
    a0 += __shfl_down(a0, off, 64);
    a1 += __shfl_down(a1, off, 64);
  }
  __shared__ float r0[4], r1[4];
  if ((tid & 63) == 0){ r0[tid >> 6] = a0; r1[tid >> 6] = a1; }
  __syncthreads();
  if (tid == 0){
    float l0 = r0[0]+r0[1]+r0[2]+r0[3] + bfc[0];
    float l1 = r1[0]+r1[1]+r1[2]+r1[3] + bfc[1];
    float mx = fmaxf(l0, l1);
    float lse = mx + logf(__expf(l0 - mx) + __expf(l1 - mx));
    rowloss[b] = lse - (targets[b] ? l1 : l0);
  }
}

__global__ __launch_bounds__(256) void k_loss(const float* __restrict__ rowloss, float* __restrict__ out){
  int tid = threadIdx.x;
  float v = rowloss[tid];
#pragma unroll
  for (int off = 32; off > 0; off >>= 1) v += __shfl_down(v, off, 64);
  __shared__ float r[4];
  if ((tid & 63) == 0) r[tid >> 6] = v;
  __syncthreads();
  if (tid == 0) out[0] = (r[0] + r[1] + r[2] + r[3]) * (1.f / B_);
}

extern "C" void kernel_launch(void* const* d_in, const int* in_sizes, int n_in,
                              void* d_out, int out_size, void* d_ws, size_t ws_size,
                              hipStream_t stream){
  (void)in_sizes; (void)n_in; (void)out_size;
  const int*   items   = (const int*)  d_in[0];
  const int*   actions = (const int*)  d_in[1];
  const int*   targets = (const int*)  d_in[2];
  const float* wt_f    = (const float*)d_in[3];
  const float* whh_f   = (const float*)d_in[4];
  const float* b_f     = (const float*)d_in[5];
  const float* wt_b    = (const float*)d_in[6];
  const float* whh_b   = (const float*)d_in[7];
  const float* b_b     = (const float*)d_in[8];
  const float* wfc     = (const float*)d_in[9];
  const float* bfc     = (const float*)d_in[10];

  char* ws = (char*)d_ws;
  uint16_t* w2t   = (uint16_t*)(ws + OFF_W2T);
  int*      lens  = (int*)     (ws + OFF_LENS);
  float*    rlbuf = (float*)   (ws + OFF_RL);
  u32*      bar   = (u32*)     (ws + OFF_BAR);
  uint16_t* hbuf  = (uint16_t*)(ws + OFF_H);

  // rotation depth gated by workspace size
  int R = 0;
  if      (ws_size >= OFF_H + 16u * SZ_HBUF) R = 16;
  else if (ws_size >= OFF_H +  8u * SZ_HBUF) R = 8;
  else if (ws_size >= OFF_H +  4u * SZ_HBUF) R = 4;
  int rmask = R ? (R - 1) : 1;

  hipFuncSetAttribute((const void*)k_persist<true>,
                      hipFuncAttributeMaxDynamicSharedMemorySize, LDS_BYTES);
  hipFuncSetAttribute((const void*)k_persist<false>,
                      hipFuncAttributeMaxDynamicSharedMemorySize, LDS_BYTES);

  hipLaunchKernelGGL(k_prep_w, dim3(8192), dim3(256), 0, stream, whh_f, whh_b, w2t);
  hipLaunchKernelGGL(k_init,   dim3(257),  dim3(256), 0, stream, hbuf, lens, bar, items);

  void* args[] = { (void*)&items, (void*)&actions, (void*)&wt_f, (void*)&wt_b,
                   (void*)&b_f, (void*)&b_b, (void*)&w2t, (void*)&hbuf,
                   (void*)&lens, (void*)&bar, (void*)&rmask };
  if (R)
    hipLaunchCooperativeKernel((const void*)k_persist<true>, dim3(256), dim3(256),
                               args, LDS_BYTES, stream);
  else
    hipLaunchCooperativeKernel((const void*)k_persist<false>, dim3(256), dim3(256),
                               args, LDS_BYTES, stream);

  // final h is always slot 0 (256 ≡ 0 mod R for R in {2,4,8,16})
  hipLaunchKernelGGL(k_fc,   dim3(256), dim3(256), 0, stream, hbuf, wfc, bfc, targets, rlbuf);
  hipLaunchKernelGGL(k_loss, dim3(1),   dim3(256), 0, stream, rlbuf, (float*)d_out);
}